// Round 14
// baseline (177.897 us; speedup 1.0000x reference)
//
#include <hip/hip_runtime.h>
#include <hip/hip_bf16.h>
#include <math.h>
#include <stdint.h>

typedef __attribute__((ext_vector_type(8))) short short8;
typedef __attribute__((ext_vector_type(4))) float float4v;

#define DEV static __device__ __forceinline__

DEV float bflo(unsigned int u) { union { unsigned int i; float f; } v; v.i = u << 16; return v.f; }
DEV float bfhi(unsigned int u) { union { unsigned int i; float f; } v; v.i = u & 0xffff0000u; return v.f; }
DEV unsigned short f2bf(float f) {
    union { float f; unsigned int i; } v; v.f = f;
    unsigned int x = v.i;
    return (unsigned short)((x + 0x7fffu + ((x >> 16) & 1u)) >> 16);
}
DEV unsigned int pack2(float a, float b) { return (unsigned int)f2bf(a) | ((unsigned int)f2bf(b) << 16); }
#if __has_builtin(__builtin_amdgcn_cvt_pk_bf16_f32)
DEV unsigned int pack2_fast(float a, float b) {
    typedef __attribute__((ext_vector_type(2))) short short2v;
    short2v r = __builtin_amdgcn_cvt_pk_bf16_f32(a, b);
    union { short2v s; unsigned int u; } v; v.s = r; return v.u;
}
#else
DEV unsigned int pack2_fast(float a, float b) { return pack2(a, b); }
#endif
DEV void unpack8(uint4 u, float* f) {
    f[0]=bflo(u.x); f[1]=bfhi(u.x); f[2]=bflo(u.y); f[3]=bfhi(u.y);
    f[4]=bflo(u.z); f[5]=bfhi(u.z); f[6]=bflo(u.w); f[7]=bfhi(u.w);
}

DEV void async16(const unsigned short* g, unsigned short* l) {
    __builtin_amdgcn_global_load_lds(
        (const __attribute__((address_space(1))) unsigned int*)g,
        (__attribute__((address_space(3))) unsigned int*)l, 16, 0, 0);
}

// ---------------------------------------------------------------------------
// K0: prep = cast f32->bf16 (lt, rt, 4 match kernels) + rsq (f64) + w1 transpose
//      + rt^T bf16 [b][512 d][128 r] for the MFMA PV in the attn role.
// ---------------------------------------------------------------------------
__global__ __launch_bounds__(256) void prep_kernel(const float* __restrict__ lt,
                                                   const float* __restrict__ rt,
                                                   const float* __restrict__ kf,
                                                   const float* __restrict__ kmp,
                                                   const float* __restrict__ ka,
                                                   const float* __restrict__ km,
                                                   const float* __restrict__ w1,
                                                   unsigned short* __restrict__ ltb,
                                                   unsigned short* __restrict__ rtb,
                                                   unsigned short* __restrict__ kb,
                                                   unsigned short* __restrict__ w1t,
                                                   unsigned short* __restrict__ rtbT,
                                                   double* __restrict__ rsq) {
    __shared__ double ws2[2][2];
    __shared__ float tile[32][33];
    int bid = blockIdx.x, t = threadIdx.x;
    if (bid < 1024) {
        bool isRt = bid >= 512;
        int base = (isRt ? (bid - 512) : bid) * 8;
        int rl = t >> 7;
        int c  = t & 127;
        const float* srcb = isRt ? rt : lt;
        unsigned short* dstb = isRt ? rtb : ltb;
        #pragma unroll
        for (int p = 0; p < 4; ++p) {
            int row = base + p * 2 + rl;
            const float* src = srcb + (size_t)row * 512;
            float4 v = *(const float4*)(src + c * 4);
            ushort4 o;
            o.x = f2bf(v.x); o.y = f2bf(v.y); o.z = f2bf(v.z); o.w = f2bf(v.w);
            *(ushort4*)(dstb + (size_t)row * 512 + c * 4) = o;
            if (isRt) {
                double s = (double)v.x * v.x + (double)v.y * v.y
                         + (double)v.z * v.z + (double)v.w * v.w;
                #pragma unroll
                for (int off = 1; off < 64; off <<= 1) s += __shfl_xor(s, off, 64);
                if ((c & 63) == 0) ws2[rl][c >> 6] = s;
                __syncthreads();
                if (c == 0) rsq[row] = 1.0 / sqrt(ws2[rl][0] + ws2[rl][1]);
                __syncthreads();
            }
        }
    } else if (bid < 1152) {
        int kbk = bid - 1024;
        int ksel = kbk >> 5;
        const float* src = (ksel == 0) ? kf : (ksel == 1) ? kmp : (ksel == 2) ? ka : km;
        int off = (kbk & 31) * 1024 + t * 4;
        float4 v = *(const float4*)(src + off);
        ushort4 o;
        o.x = f2bf(v.x); o.y = f2bf(v.y); o.z = f2bf(v.z); o.w = f2bf(v.w);
        *(ushort4*)(kb + ksel * 32768 + off) = o;
    } else if (bid < 1216) {
        int b2 = bid - 1152;
        int d0 = (b2 & 15) * 32, a0 = (b2 >> 4) * 32;
        int r = t >> 5, c = t & 31;
        #pragma unroll
        for (int i = 0; i < 32; i += 8)
            tile[r + i][c] = w1[(size_t)(d0 + r + i) * 128 + a0 + c];
        __syncthreads();
        #pragma unroll
        for (int i = 0; i < 32; i += 8)
            w1t[(size_t)(a0 + r + i) * 512 + d0 + c] = f2bf(tile[c][r + i]);
    } else {
        // rt^T: rtbT[b][d][r] = f2bf(rt[b][r][d]); 32x32 tiles.
        int b3 = bid - 1216;               // 0..2047
        int b = b3 >> 6;
        int tid = b3 & 63;
        int d0 = (tid & 15) * 32;          // 16 d-tiles
        int r0 = (tid >> 4) * 32;          // 4 r-tiles
        int r = t >> 5, c = t & 31;
        #pragma unroll
        for (int i = 0; i < 32; i += 8)
            tile[r + i][c] = rt[(size_t)(b * 128 + r0 + r + i) * 512 + d0 + c];
        __syncthreads();
        #pragma unroll
        for (int i = 0; i < 32; i += 8)
            rtbT[(size_t)(b * 512 + d0 + r + i) * 128 + r0 + c] = f2bf(tile[c][r + i]);
    }
}

// ---------------------------------------------------------------------------
// K1: uber = mpool [0,2048) + score [2048,2080) + proj [2080,2336)
// R7/R11-verified at ~73.4us (double-buffered rt; 52224 LDS; 3 blocks/CU).
// ---------------------------------------------------------------------------
__global__ __launch_bounds__(256, 3) void uber_kernel(
        const unsigned short* __restrict__ ltb,
        const unsigned short* __restrict__ rtb,
        const unsigned short* __restrict__ kmb,
        const unsigned short* __restrict__ w1t,
        const float* __restrict__ diag,
        unsigned short* __restrict__ a_all,
        const double* __restrict__ rsq,
        unsigned int* __restrict__ candp,
        float* __restrict__ out) {
    __shared__ __align__(16) unsigned char smem[52224];
    int bx = blockIdx.x;
    int t = threadIdx.x;
    int wave = t >> 6, lane = t & 63;
    int q = lane >> 4, col = lane & 15, kq = q * 8;

    if (bx < 2048) {
        // ================= mpool role =================
        int xcd = bx & 7, jj = bx >> 3;
        int b = xcd * 4 + (jj >> 6);
        int m = jj & 63;
        unsigned short* ltS = (unsigned short*)smem;            // 16384 B, XOR-slot layout
        unsigned short* rtL = (unsigned short*)(smem + 16384);  // 2 x 16384 B, swizzled
        float (*mx)[2] = (float(*)[2])(smem + 16384 + 32768);   // 1024 B
        int wl = wave & 1, wr = wave >> 1;
        const unsigned short* ltp = ltb + (size_t)b * 65536;
        const unsigned short* rtp = rtb + (size_t)b * 65536;
        const unsigned short* kr = kmb + (size_t)m * 512;
        int srow = t >> 3, cg8 = t & 7, cg = cg8 * 8;
        int gsw = (cg8 ^ (srow & 7)) * 8;
        int wbase = (t & ~63) * 8;

        #pragma unroll
        for (int it = 0; it < 4; ++it)
            async16(rtp + (size_t)(it * 32 + srow) * 512 + gsw,
                    rtL + it * 2048 + wbase);
        uint4 pk = *(const uint4*)(kr + cg);
        uint4 plt[4];
        #pragma unroll
        for (int it = 0; it < 4; ++it)
            plt[it] = *(const uint4*)(ltp + (size_t)(it * 32 + srow) * 512 + cg);

        float4v acc[4][4] = {};
        for (int k0i = 0; k0i < 8; ++k0i) {
            float kf8[8]; unpack8(pk, kf8);
            #pragma unroll
            for (int it = 0; it < 4; ++it) {
                int row = it * 32 + srow;
                float lf[8]; unpack8(plt[it], lf);
                uint4 s;
                s.x = pack2_fast(lf[0] * kf8[0], lf[1] * kf8[1]);
                s.y = pack2_fast(lf[2] * kf8[2], lf[3] * kf8[3]);
                s.z = pack2_fast(lf[4] * kf8[4], lf[5] * kf8[5]);
                s.w = pack2_fast(lf[6] * kf8[6], lf[7] * kf8[7]);
                *(uint4*)&ltS[row * 64 + gsw] = s;
            }
            __syncthreads();
            if (k0i < 7) {
                int k0n = (k0i + 1) * 64;
                int bofs = ((k0i + 1) & 1) * 8192;
                #pragma unroll
                for (int it = 0; it < 4; ++it)
                    async16(rtp + (size_t)(it * 32 + srow) * 512 + k0n + gsw,
                            rtL + bofs + it * 2048 + wbase);
                pk = *(const uint4*)(kr + k0n + cg);
                #pragma unroll
                for (int it = 0; it < 4; ++it)
                    plt[it] = *(const uint4*)(ltp + (size_t)(it * 32 + srow) * 512 + k0n + cg);
            }
            const unsigned short* rb = rtL + (k0i & 1) * 8192;
            #pragma unroll
            for (int kk = 0; kk < 64; kk += 32) {
                short8 af[4], bfr[4];
                #pragma unroll
                for (int i = 0; i < 4; ++i) {
                    int rowA = wl * 64 + i * 16 + col;
                    int slotA = ((kk >> 3) + q) ^ (rowA & 7);
                    af[i] = *(const short8*)&ltS[rowA * 64 + slotA * 8];
                }
                #pragma unroll
                for (int j = 0; j < 4; ++j) {
                    int row = wr * 64 + j * 16 + col;
                    int slot = ((kk >> 3) + q) ^ (row & 7);
                    bfr[j] = *(const short8*)&rb[row * 64 + slot * 8];
                }
                #pragma unroll
                for (int i = 0; i < 4; ++i)
                    #pragma unroll
                    for (int j = 0; j < 4; ++j)
                        acc[i][j] = __builtin_amdgcn_mfma_f32_16x16x32_bf16(af[i], bfr[j], acc[i][j], 0, 0, 0);
            }
            __syncthreads();
        }
        #pragma unroll
        for (int i = 0; i < 4; ++i)
            #pragma unroll
            for (int ii = 0; ii < 4; ++ii) {
                float v = fmaxf(fmaxf(acc[i][0][ii], acc[i][1][ii]), fmaxf(acc[i][2][ii], acc[i][3][ii]));
                #pragma unroll
                for (int off = 1; off < 16; off <<= 1) v = fmaxf(v, __shfl_xor(v, off, 64));
                if (col == 0) mx[wl * 64 + i * 16 + q * 4 + ii][wr] = v;
            }
        __syncthreads();
        if (t < 128)
            out[((size_t)(b * 128 + t)) * 259 + 65 + m] = tanhf(fmaxf(mx[t][0], mx[t][1]));

    } else if (bx < 2080) {
        // ================= score role (argmax candidates via MFMA) ===========
        int sb = bx - 2048;                 // [0,32)
        int xcd = sb & 7;
        int b = xcd * 4 + (sb >> 3);
        unsigned short* ltS = (unsigned short*)smem;            // 16384 B
        unsigned short* rtL = (unsigned short*)(smem + 16384);  // 2 x 16384 B
        float* rsqf = (float*)(smem + 49152);                   // 512 B
        unsigned int (*candL)[2] = (unsigned int(*)[2])(smem + 49664); // 1024 B
        int wl = wave & 1, wr = wave >> 1;
        const unsigned short* ltp = ltb + (size_t)b * 65536;
        const unsigned short* rtp = rtb + (size_t)b * 65536;
        int srow = t >> 3, cg8 = t & 7, cg = cg8 * 8;
        int gsw = (cg8 ^ (srow & 7)) * 8;
        int wbase = (t & ~63) * 8;

        #pragma unroll
        for (int it = 0; it < 4; ++it)
            async16(rtp + (size_t)(it * 32 + srow) * 512 + gsw,
                    rtL + it * 2048 + wbase);
        uint4 plt[4];
        #pragma unroll
        for (int it = 0; it < 4; ++it)
            plt[it] = *(const uint4*)(ltp + (size_t)(it * 32 + srow) * 512 + cg);
        if (t < 128) rsqf[t] = (float)rsq[b * 128 + t];

        float4v acc[4][4] = {};
        for (int k0i = 0; k0i < 8; ++k0i) {
            #pragma unroll
            for (int it = 0; it < 4; ++it) {
                int row = it * 32 + srow;
                *(uint4*)&ltS[row * 64 + gsw] = plt[it];   // raw lt (no scale)
            }
            __syncthreads();
            if (k0i < 7) {
                int k0n = (k0i + 1) * 64;
                int bofs = ((k0i + 1) & 1) * 8192;
                #pragma unroll
                for (int it = 0; it < 4; ++it)
                    async16(rtp + (size_t)(it * 32 + srow) * 512 + k0n + gsw,
                            rtL + bofs + it * 2048 + wbase);
                #pragma unroll
                for (int it = 0; it < 4; ++it)
                    plt[it] = *(const uint4*)(ltp + (size_t)(it * 32 + srow) * 512 + k0n + cg);
            }
            const unsigned short* rb = rtL + (k0i & 1) * 8192;
            #pragma unroll
            for (int kk = 0; kk < 64; kk += 32) {
                short8 af[4], bfr[4];
                #pragma unroll
                for (int i = 0; i < 4; ++i) {
                    int rowA = wl * 64 + i * 16 + col;
                    int slotA = ((kk >> 3) + q) ^ (rowA & 7);
                    af[i] = *(const short8*)&ltS[rowA * 64 + slotA * 8];
                }
                #pragma unroll
                for (int j = 0; j < 4; ++j) {
                    int row = wr * 64 + j * 16 + col;
                    int slot = ((kk >> 3) + q) ^ (row & 7);
                    bfr[j] = *(const short8*)&rb[row * 64 + slot * 8];
                }
                #pragma unroll
                for (int i = 0; i < 4; ++i)
                    #pragma unroll
                    for (int j = 0; j < 4; ++j)
                        acc[i][j] = __builtin_amdgcn_mfma_f32_16x16x32_bf16(af[i], bfr[j], acc[i][j], 0, 0, 0);
            }
            __syncthreads();
        }
        // top-2 over this wave's 64 rt-cols per lt-row; 4 cands/row total.
        float rq[4];
        #pragma unroll
        for (int j = 0; j < 4; ++j) rq[j] = rsqf[wr * 64 + j * 16 + col];
        #pragma unroll
        for (int i = 0; i < 4; ++i)
            #pragma unroll
            for (int ii = 0; ii < 4; ++ii) {
                float v1 = -3.0e38f, v2 = -3.0e38f; int i1 = 0, i2 = 1;
                #pragma unroll
                for (int j = 0; j < 4; ++j) {
                    int rc = wr * 64 + j * 16 + col;
                    float s = acc[i][j][ii] * rq[j];
                    if (s > v1) { v2 = v1; i2 = i1; v1 = s; i1 = rc; }
                    else if (s > v2) { v2 = s; i2 = rc; }
                }
                #pragma unroll
                for (int off = 1; off < 16; off <<= 1) {
                    float u1 = __shfl_xor(v1, off, 64); int j1 = __shfl_xor(i1, off, 64);
                    float u2 = __shfl_xor(v2, off, 64); int j2 = __shfl_xor(i2, off, 64);
                    if (u1 > v1) {
                        float ov = v1; int oi = i1;
                        v1 = u1; i1 = j1;
                        if (u2 > ov) { v2 = u2; i2 = j2; } else { v2 = ov; i2 = oi; }
                    } else if (u1 > v2) { v2 = u1; i2 = j1; }
                }
                if (col == 0)
                    candL[wl * 64 + i * 16 + q * 4 + ii][wr] =
                        (unsigned int)i1 | ((unsigned int)i2 << 8);
            }
        __syncthreads();
        if (t < 128)
            candp[b * 128 + t] = candL[t][0] | (candL[t][1] << 16);

    } else {
        // ================= proj role =================
        int R0 = (bx - 2080) * 32;
        unsigned short (*aS)[72] = (unsigned short(*)[72])smem;
        unsigned short (*bS)[72] = (unsigned short(*)[72])(smem + 4608);
        float* diagS = (float*)(smem + 4608 + 18432);
        int wl = wave & 1, wr = wave >> 1;
        if (t < 128) diagS[t] = diag[t];
        const unsigned short* src = (R0 < 4096) ? (ltb + (size_t)R0 * 512) : (rtb + (size_t)(R0 - 4096) * 512);
        float4v acc[4] = {};
        for (int k0 = 0; k0 < 512; k0 += 64) {
            {
                int row = t >> 3, cg = (t & 7) * 8;
                *(uint4*)&aS[row][cg] = *(const uint4*)(src + (size_t)row * 512 + k0 + cg);
            }
            #pragma unroll
            for (int it = 0; it < 4; ++it) {
                int id = it * 256 + t;
                int row = id >> 3, cg = (id & 7) * 8;
                *(uint4*)&bS[row][cg] = *(const uint4*)(w1t + (size_t)row * 512 + k0 + cg);
            }
            __syncthreads();
            #pragma unroll
            for (int kk = 0; kk < 64; kk += 32) {
                short8 af = *(const short8*)&aS[wl * 16 + col][kk + kq];
                #pragma unroll
                for (int j = 0; j < 4; ++j) {
                    short8 bf = *(const short8*)&bS[wr * 64 + j * 16 + col][kk + kq];
                    acc[j] = __builtin_amdgcn_mfma_f32_16x16x32_bf16(af, bf, acc[j], 0, 0, 0);
                }
            }
            __syncthreads();
        }
        bool isLt = (R0 < 4096);
        #pragma unroll
        for (int j = 0; j < 4; ++j)
            #pragma unroll
            for (int ii = 0; ii < 4; ++ii) {
                int rowl = wl * 16 + q * 4 + ii;
                int n = wr * 64 + j * 16 + col;
                float v = tanhf(acc[j][ii]);
                if (isLt) v *= diagS[n];
                a_all[((size_t)(R0 + rowl)) * 128 + n] = f2bf(v);
            }
    }
}

// ---------------------------------------------------------------------------
// K2: tail = attn [0,256) + mpmatch [256,768). R11-verified (3 blocks/CU,
// LDS 53504, f32 attF, bit-identical canary 0.01367188).
// ---------------------------------------------------------------------------
__global__ __launch_bounds__(512, 6) void tail_kernel(
        const unsigned short* __restrict__ a_all,
        const unsigned short* __restrict__ rtb,
        const unsigned short* __restrict__ rtbT,
        const float* __restrict__ ltf,
        const float* __restrict__ rtf,
        const double* __restrict__ rsq,
        const unsigned short* __restrict__ kb,
        const float* __restrict__ hfw,
        const float* __restrict__ hbw,
        const unsigned int* __restrict__ candp,
        float* __restrict__ out) {
    __shared__ __align__(16) unsigned char smem[53504];
    int bx = blockIdx.x;
    int t = threadIdx.x;
    int wave = t >> 6, lane = t & 63;
    int q = lane >> 4, col = lane & 15, kq = q * 8;

    if (bx < 256) {
        // ================= attn role =================
        int b = bx & 31, lg = bx >> 5;
        int L0 = lg * 16;
        // Phase-1 layout: altS[0,4352) artS[4352,39168) pmax[39168) psum[39680)
        unsigned short (*altS)[136]  = (unsigned short(*)[136])(smem);
        unsigned short (*artS)[136]  = (unsigned short(*)[136])(smem + 4352);
        float (*pmax)[8] = (float(*)[8])(smem + 39168);
        float (*psum)[8] = (float(*)[8])(smem + 39680);
        const unsigned short* kb_att = kb + 2 * 32768;

        if (t < 256) {
            int row = t >> 4, c0 = (t & 15) * 8;
            *(uint4*)&altS[row][c0] = *(const uint4*)(a_all + ((size_t)(b * 128 + L0 + row)) * 128 + c0);
        }
        {
            int row = t >> 2, c0 = (t & 3) * 32;
            const unsigned short* src = a_all + ((size_t)(4096 + b * 128 + row)) * 128 + c0;
            #pragma unroll
            for (int i = 0; i < 4; ++i)
                *(uint4*)&artS[row][c0 + i * 8] = *(const uint4*)(src + i * 8);
        }
        __syncthreads();

        float4v acc = {};
        #pragma unroll
        for (int kk = 0; kk < 128; kk += 32) {
            short8 af = *(const short8*)&altS[col][kk + kq];
            short8 bf = *(const short8*)&artS[wave * 16 + col][kk + kq];
            acc = __builtin_amdgcn_mfma_f32_16x16x32_bf16(af, bf, acc, 0, 0, 0);
        }
        float m4[4], p4[4];
        #pragma unroll
        for (int ii = 0; ii < 4; ++ii) {
            float v = acc[ii];
            #pragma unroll
            for (int off = 1; off < 16; off <<= 1) v = fmaxf(v, __shfl_xor(v, off, 64));
            m4[ii] = v;
        }
        if (col == 0) {
            #pragma unroll
            for (int ii = 0; ii < 4; ++ii) pmax[q * 4 + ii][wave] = m4[ii];
        }
        __syncthreads();
        #pragma unroll
        for (int ii = 0; ii < 4; ++ii) {
            float M = pmax[q * 4 + ii][0];
            #pragma unroll
            for (int w = 1; w < 8; ++w) M = fmaxf(M, pmax[q * 4 + ii][w]);
            p4[ii] = expf(acc[ii] - M);
            float sv = p4[ii];
            #pragma unroll
            for (int off = 1; off < 16; off <<= 1) sv += __shfl_xor(sv, off, 64);
            m4[ii] = sv;
        }
        if (col == 0) {
            #pragma unroll
            for (int ii = 0; ii < 4; ++ii) psum[q * 4 + ii][wave] = m4[ii];
        }
        __syncthreads();
        // P -> bf16 into the altS region (scores reads done)
        unsigned short* Pb = (unsigned short*)smem;
        #pragma unroll
        for (int ii = 0; ii < 4; ++ii) {
            float S = psum[q * 4 + ii][0] + psum[q * 4 + ii][1] + psum[q * 4 + ii][2] + psum[q * 4 + ii][3]
                    + psum[q * 4 + ii][4] + psum[q * 4 + ii][5] + psum[q * 4 + ii][6] + psum[q * 4 + ii][7];
            Pb[(q * 4 + ii) * 136 + wave * 16 + col] = f2bf(p4[ii] / S);
        }

        // ---- PV via MFMA: 4cc x 2rh chunks of 16 KB (128 d-rows x 64 r) ----
        // PV layout: Pb[0,4352) Bc[4352,20736) attF[20736,53504)
        unsigned short* Bc = (unsigned short*)(smem + 4352);
        float* attF = (float*)(smem + 20736);                   // [16][512] f32
        const unsigned short* rtT = rtbT + (size_t)b * 65536;
        for (int cc = 0; cc < 4; ++cc) {
            float4v pacc = {};
            for (int rh = 0; rh < 2; ++rh) {
                #pragma unroll
                for (int k = 0; k < 2; ++k) {
                    int id = (k * 8 + wave) * 64 + lane;        // [0,1024)
                    int row = id >> 3, grp = id & 7;
                    int d   = (row >> 4) * 64 + cc * 16 + (row & 15);
                    int sg  = grp ^ (row & 7);
                    async16(rtT + (size_t)d * 128 + rh * 64 + sg * 8,
                            Bc + (size_t)id * 8);
                }
                __syncthreads();   // chunk landed (first iter: Pb also ready)
                #pragma unroll
                for (int ks = 0; ks < 2; ++ks) {
                    short8 afP = *(const short8*)&Pb[col * 136 + rh * 64 + ks * 32 + kq];
                    int rowB = wave * 16 + col;
                    short8 bfB = *(const short8*)&Bc[rowB * 64 + (((ks * 4 + q) ^ (rowB & 7)) * 8)];
                    pacc = __builtin_amdgcn_mfma_f32_16x16x32_bf16(afP, bfB, pacc, 0, 0, 0);
                }
                __syncthreads();   // guard Bc overwrite
            }
            #pragma unroll
            for (int ii = 0; ii < 4; ++ii)
                attF[(q * 4 + ii) * 512 + wave * 64 + cc * 16 + col] = pacc[ii];
        }
        __syncthreads();           // attF complete

        int l = t >> 5, cd = t & 31;
        float a8[2][8];
        #pragma unroll
        for (int pass = 0; pass < 2; ++pass) {
            *(float4*)&a8[pass][0] = *(const float4*)&attF[l * 512 + pass * 256 + cd * 8];
            *(float4*)&a8[pass][4] = *(const float4*)&attF[l * 512 + pass * 256 + cd * 8 + 4];
        }
        __syncthreads();           // att reads done before region reuse

        // Post-PV layout (mpmatch-style): prodsF[0,16640) Ks[16640,49920),
        // red aliases Ks (pre-write barrier).
        unsigned short (*prodsF)[520] = (unsigned short(*)[520])smem;
        unsigned short* Ks = (unsigned short*)(smem + 16640);
        float* red = (float*)(smem + 16640);

        int grow = b * 128 + L0 + l;
        const float* ltrow = ltf + (size_t)grow * 512;
        float csum = 0.f;
        #pragma unroll
        for (int pass = 0; pass < 2; ++pass) {
            int d0 = pass * 256 + cd * 8;
            float lf[8];
            *(float4*)&lf[0] = *(const float4*)(ltrow + d0);
            *(float4*)&lf[4] = *(const float4*)(ltrow + d0 + 4);
            float pf[8];
            #pragma unroll
            for (int k = 0; k < 8; ++k) { pf[k] = lf[k] * a8[pass][k]; csum += pf[k]; }
            uint4 o;
            o.x = pack2(pf[0], pf[1]); o.y = pack2(pf[2], pf[3]);
            o.z = pack2(pf[4], pf[5]); o.w = pack2(pf[6], pf[7]);
            *(uint4*)&prodsF[l][d0] = o;
        }
        #pragma unroll
        for (int off = 1; off < 32; off <<= 1) csum += __shfl_xor(csum, off, 64);
        if (cd == 0) out[(size_t)grow * 259 + 129] = tanhf(csum);

        for (int half = 0; half < 2; ++half) {
            __syncthreads();       // prodsF ready / prior red reads done
            {
                int row = t >> 4, c0 = (t & 15) * 32;
                const unsigned short* src = kb_att + ((size_t)(half * 32 + row)) * 512 + c0;
                #pragma unroll
                for (int i = 0; i < 4; ++i)
                    *(uint4*)&Ks[row * 520 + c0 + i * 8] = *(const uint4*)(src + i * 8);
            }
            __syncthreads();
            float4v pacc[2] = {};
            #pragma unroll
            for (int kk = 0; kk < 64; kk += 32) {
                short8 af = *(const short8*)&prodsF[col][wave * 64 + kk + kq];
                #pragma unroll
                for (int j = 0; j < 2; ++j) {
                    short8 bf = *(const short8*)&Ks[(j * 16 + col) * 520 + wave * 64 + kk + kq];
                    pacc[j] = __builtin_amdgcn_mfma_f32_16x16x32_bf16(af, bf, pacc[j], 0, 0, 0);
                }
            }
            __syncthreads();       // all Ks reads done before red overwrites
            #pragma unroll
            for (int j = 0; j < 2; ++j)
                #pragma unroll
                for (int ii = 0; ii < 4; ++ii)
                    red[((wave * 2 + j) * 16 + q * 4 + ii) * 16 + col] = pacc[j][ii];
            __syncthreads();
            {
                int ll = t >> 5, jm = t & 31;
                int j = jm >> 4, mc = jm & 15;
                float sv = 0.f;
                #pragma unroll
                for (int w = 0; w < 8; ++w) sv += red[((w * 2 + j) * 16 + ll) * 16 + mc];
                out[((size_t)(b * 128 + L0 + ll)) * 259 + 130 + half * 32 + jm] = tanhf(sv);
            }
        }

    } else {
        // ================= mpmatch role (sequential 32-m halves) =============
        int idB = bx - 256;
        int lg = idB & 7, b = (idB >> 3) & 31;
        int mode = (idB >> 8) ? 2 : 0;
        int L0 = lg * 16;
        unsigned short (*prods)[520] = (unsigned short(*)[520])smem;   // [0,16640)
        unsigned short* Ks = (unsigned short*)(smem + 16640);          // [16640,49920)
        float* red = (float*)(smem + 16640);                           // aliases Ks
        double* dvs2 = (double*)(smem + 49920);                        // 512
        int* idxl = (int*)(smem + 50432);                              // 64
        const unsigned short* Kp = kb + (size_t)((mode == 0) ? 0 : 3 * 32768);
        int obase = (mode == 0) ? 0 : 194;

        if (mode == 2) {
            // f64-rescore the 4 candidates per lt row, pick exact best.
            int dotid = t >> 3, sub = t & 7;     // 64 dots x 8 threads
            int l = dotid >> 2, c = dotid & 3;
            unsigned int cpl = candp[b * 128 + L0 + l];
            int rr0 = (cpl >> (c * 8)) & 0xff;
            const float* lrow = ltf + ((size_t)(b * 128 + L0 + l)) * 512;
            const float* rrow = rtf + ((size_t)(b * 128 + rr0)) * 512;
            double sv = 0.0;
            #pragma unroll 8
            for (int k = 0; k < 64; ++k) {
                int d = sub * 64 + k;
                sv = fma((double)lrow[d], (double)rrow[d], sv);
            }
            #pragma unroll
            for (int off = 1; off < 8; off <<= 1) sv += __shfl_xor(sv, off, 64);
            if (sub == 0) dvs2[dotid] = sv * rsq[b * 128 + rr0];
            __syncthreads();
            if (t < 16) {
                unsigned int cl = candp[b * 128 + L0 + t];
                int bi = 256; double bv = -1.0e300;
                #pragma unroll
                for (int cc = 0; cc < 4; ++cc) {
                    int rr = (cl >> (cc * 8)) & 0xff;
                    double v = dvs2[t * 4 + cc];
                    if (v > bv || (v == bv && rr < bi)) { bv = v; bi = rr; }
                }
                idxl[t] = bi;
            }
            __syncthreads();
        }

        if (t < 256) {
            int l = t >> 4, c = t & 15;
            int grow = b * 128 + L0 + l;
            const float* ltrow = ltf + (size_t)grow * 512;
            const unsigned short* avrow = 0;
            if (mode == 2) avrow = rtb + ((size_t)(b * 128 + idxl[l])) * 512;
            float csum = 0.f;
            #pragma unroll
            for (int pass = 0; pass < 4; ++pass) {
                int d0 = pass * 128 + c * 8;
                float lf[8], af[8], pf[8];
                *(float4*)&lf[0] = *(const float4*)(ltrow + d0);
                *(float4*)&lf[4] = *(const float4*)(ltrow + d0 + 4);
                if (mode == 0) {
                    const float* h = (d0 < 256) ? (hfw + b * 256 + d0) : (hbw + b * 256 + d0 - 256);
                    *(float4*)&af[0] = *(const float4*)h;
                    *(float4*)&af[4] = *(const float4*)(h + 4);
                } else {
                    uint4 av = *(const uint4*)(avrow + d0);
                    unpack8(av, af);
                }
                #pragma unroll
                for (int k = 0; k < 8; ++k) { pf[k] = lf[k] * af[k]; csum += pf[k]; }
                uint4 o;
                o.x = pack2(pf[0], pf[1]); o.y = pack2(pf[2], pf[3]);
                o.z = pack2(pf[4], pf[5]); o.w = pack2(pf[6], pf[7]);
                *(uint4*)&prods[l][d0] = o;
            }
            #pragma unroll
            for (int off = 1; off < 16; off <<= 1) csum += __shfl_xor(csum, off, 64);
            if (c == 0) out[(size_t)grow * 259 + obase] = tanhf(csum);
        }
        for (int half = 0; half < 2; ++half) {
            if (half == 1) __syncthreads();    // prior red reads done before restage
            {   // stage 32 K rows (512 threads, 32B each)
                int row = t >> 4, c0 = (t & 15) * 32;
                const unsigned short* src = Kp + ((size_t)(half * 32 + row)) * 512 + c0;
                #pragma unroll
                for (int i = 0; i < 4; ++i)
                    *(uint4*)&Ks[row * 520 + c0 + i * 8] = *(const uint4*)(src + i * 8);
            }
            __syncthreads();   // prods + Ks ready
            float4v acc2[2] = {};
            #pragma unroll
            for (int kk = 0; kk < 64; kk += 32) {
                short8 af = *(const short8*)&prods[col][wave * 64 + kk + kq];
                #pragma unroll
                for (int j = 0; j < 2; ++j) {
                    short8 bf = *(const short8*)&Ks[(j * 16 + col) * 520 + wave * 64 + kk + kq];
                    acc2[j] = __builtin_amdgcn_mfma_f32_16x16x32_bf16(af, bf, acc2[j], 0, 0, 0);
                }
            }
            __syncthreads();   // all Ks reads done before red overwrites
            #pragma unroll
            for (int j = 0; j < 2; ++j)
                #pragma unroll
                for (int ii = 0; ii < 4; ++ii)
                    red[((wave * 2 + j) * 16 + q * 4 + ii) * 16 + col] = acc2[j][ii];
            __syncthreads();   // red ready
            {
                int ll = t >> 5, jm = t & 31;
                int j = jm >> 4, mc = jm & 15;
                float sv = 0.f;
                #pragma unroll
                for (int w = 0; w < 8; ++w) sv += red[((w * 2 + j) * 16 + ll) * 16 + mc];
                out[((size_t)(b * 128 + L0 + ll)) * 259 + obase + 1 + half * 32 + jm] = tanhf(sv);
            }
        }
    }
}

// ---------------------------------------------------------------------------
extern "C" void kernel_launch(void* const* d_in, const int* in_sizes, int n_in,
                              void* d_out, int out_size, void* d_ws, size_t ws_size,
                              hipStream_t stream) {
    const float* lt  = (const float*)d_in[0];
    const float* rt  = (const float*)d_in[3];
    const float* hfw = (const float*)d_in[4];
    const float* hbw = (const float*)d_in[5];
    const float* kf  = (const float*)d_in[6];
    const float* kmp = (const float*)d_in[7];
    const float* w1  = (const float*)d_in[8];
    const float* dia = (const float*)d_in[9];
    const float* ka  = (const float*)d_in[10];
    const float* km  = (const float*)d_in[11];
    float* out = (float*)d_out;

    char* wsb = (char*)d_ws;
    unsigned short* ltb16 = (unsigned short*)(wsb);                        // 4 MB
    unsigned short* rtb16 = (unsigned short*)(wsb + 4194304);              // 4 MB
    unsigned short* kb16  = (unsigned short*)(wsb + 8388608);              // 256 KB
    unsigned short* w1t   = (unsigned short*)(wsb + 8650752);              // 128 KB
    unsigned short* a_all = (unsigned short*)(wsb + 8781824);              // 2 MB
    unsigned short* rtbT  = (unsigned short*)(wsb + 10878976);             // 4 MB
    double*         rsq   = (double*)(wsb + 15073280);                     // 32 KB
    unsigned int*   candp = (unsigned int*)(wsb + 15106048);               // 16 KB

    prep_kernel<<<3264, 256, 0, stream>>>(lt, rt, kf, kmp, ka, km, w1, ltb16, rtb16, kb16, w1t, rtbT, rsq);
    uber_kernel<<<2336, 256, 0, stream>>>(ltb16, rtb16, kb16 + 32768, w1t, dia, a_all,
                                          rsq, candp, out);
    tail_kernel<<<768, 512, 0, stream>>>(a_all, rtb16, rtbT, lt, rt, rsq, kb16, hfw, hbw, candp, out);
}

// Round 15
// 171.818 us; speedup vs baseline: 1.0354x; 1.0354x over previous
//
#include <hip/hip_runtime.h>
#include <hip/hip_bf16.h>
#include <math.h>
#include <stdint.h>

typedef __attribute__((ext_vector_type(8))) short short8;
typedef __attribute__((ext_vector_type(4))) float float4v;

#define DEV static __device__ __forceinline__

DEV float bflo(unsigned int u) { union { unsigned int i; float f; } v; v.i = u << 16; return v.f; }
DEV float bfhi(unsigned int u) { union { unsigned int i; float f; } v; v.i = u & 0xffff0000u; return v.f; }
DEV unsigned short f2bf(float f) {
    union { float f; unsigned int i; } v; v.f = f;
    unsigned int x = v.i;
    return (unsigned short)((x + 0x7fffu + ((x >> 16) & 1u)) >> 16);
}
DEV unsigned int pack2(float a, float b) { return (unsigned int)f2bf(a) | ((unsigned int)f2bf(b) << 16); }
#if __has_builtin(__builtin_amdgcn_cvt_pk_bf16_f32)
DEV unsigned int pack2_fast(float a, float b) {
    typedef __attribute__((ext_vector_type(2))) short short2v;
    short2v r = __builtin_amdgcn_cvt_pk_bf16_f32(a, b);
    union { short2v s; unsigned int u; } v; v.s = r; return v.u;
}
#else
DEV unsigned int pack2_fast(float a, float b) { return pack2(a, b); }
#endif
DEV void unpack8(uint4 u, float* f) {
    f[0]=bflo(u.x); f[1]=bfhi(u.x); f[2]=bflo(u.y); f[3]=bfhi(u.y);
    f[4]=bflo(u.z); f[5]=bfhi(u.z); f[6]=bflo(u.w); f[7]=bfhi(u.w);
}

DEV void async16(const unsigned short* g, unsigned short* l) {
    __builtin_amdgcn_global_load_lds(
        (const __attribute__((address_space(1))) unsigned int*)g,
        (__attribute__((address_space(3))) unsigned int*)l, 16, 0, 0);
}

// ---------------------------------------------------------------------------
// K0: prep = cast f32->bf16 (lt, rt, 4 match kernels) + rsq (f64) + w1 transpose
//      + rt^T bf16 [b][512 d][128 r] for the MFMA PV in the attn role.
// ---------------------------------------------------------------------------
__global__ __launch_bounds__(256) void prep_kernel(const float* __restrict__ lt,
                                                   const float* __restrict__ rt,
                                                   const float* __restrict__ kf,
                                                   const float* __restrict__ kmp,
                                                   const float* __restrict__ ka,
                                                   const float* __restrict__ km,
                                                   const float* __restrict__ w1,
                                                   unsigned short* __restrict__ ltb,
                                                   unsigned short* __restrict__ rtb,
                                                   unsigned short* __restrict__ kb,
                                                   unsigned short* __restrict__ w1t,
                                                   unsigned short* __restrict__ rtbT,
                                                   double* __restrict__ rsq) {
    __shared__ double ws2[2][2];
    __shared__ float tile[32][33];
    int bid = blockIdx.x, t = threadIdx.x;
    if (bid < 1024) {
        bool isRt = bid >= 512;
        int base = (isRt ? (bid - 512) : bid) * 8;
        int rl = t >> 7;
        int c  = t & 127;
        const float* srcb = isRt ? rt : lt;
        unsigned short* dstb = isRt ? rtb : ltb;
        #pragma unroll
        for (int p = 0; p < 4; ++p) {
            int row = base + p * 2 + rl;
            const float* src = srcb + (size_t)row * 512;
            float4 v = *(const float4*)(src + c * 4);
            ushort4 o;
            o.x = f2bf(v.x); o.y = f2bf(v.y); o.z = f2bf(v.z); o.w = f2bf(v.w);
            *(ushort4*)(dstb + (size_t)row * 512 + c * 4) = o;
            if (isRt) {
                double s = (double)v.x * v.x + (double)v.y * v.y
                         + (double)v.z * v.z + (double)v.w * v.w;
                #pragma unroll
                for (int off = 1; off < 64; off <<= 1) s += __shfl_xor(s, off, 64);
                if ((c & 63) == 0) ws2[rl][c >> 6] = s;
                __syncthreads();
                if (c == 0) rsq[row] = 1.0 / sqrt(ws2[rl][0] + ws2[rl][1]);
                __syncthreads();
            }
        }
    } else if (bid < 1152) {
        int kbk = bid - 1024;
        int ksel = kbk >> 5;
        const float* src = (ksel == 0) ? kf : (ksel == 1) ? kmp : (ksel == 2) ? ka : km;
        int off = (kbk & 31) * 1024 + t * 4;
        float4 v = *(const float4*)(src + off);
        ushort4 o;
        o.x = f2bf(v.x); o.y = f2bf(v.y); o.z = f2bf(v.z); o.w = f2bf(v.w);
        *(ushort4*)(kb + ksel * 32768 + off) = o;
    } else if (bid < 1216) {
        int b2 = bid - 1152;
        int d0 = (b2 & 15) * 32, a0 = (b2 >> 4) * 32;
        int r = t >> 5, c = t & 31;
        #pragma unroll
        for (int i = 0; i < 32; i += 8)
            tile[r + i][c] = w1[(size_t)(d0 + r + i) * 128 + a0 + c];
        __syncthreads();
        #pragma unroll
        for (int i = 0; i < 32; i += 8)
            w1t[(size_t)(a0 + r + i) * 512 + d0 + c] = f2bf(tile[c][r + i]);
    } else {
        // rt^T: rtbT[b][d][r] = f2bf(rt[b][r][d]); 32x32 tiles.
        int b3 = bid - 1216;               // 0..2047
        int b = b3 >> 6;
        int tid = b3 & 63;
        int d0 = (tid & 15) * 32;          // 16 d-tiles
        int r0 = (tid >> 4) * 32;          // 4 r-tiles
        int r = t >> 5, c = t & 31;
        #pragma unroll
        for (int i = 0; i < 32; i += 8)
            tile[r + i][c] = rt[(size_t)(b * 128 + r0 + r + i) * 512 + d0 + c];
        __syncthreads();
        #pragma unroll
        for (int i = 0; i < 32; i += 8)
            rtbT[(size_t)(b * 512 + d0 + r + i) * 128 + r0 + c] = f2bf(tile[c][r + i]);
    }
}

// ---------------------------------------------------------------------------
// K1: uber = mpool2 [0,1024) + score [1024,1056) + proj [1056,1312)
// R15: mpool processes TWO m-values per block (m0=2j, m0+1). Per k0i: unpack
// lt once, produce two K-scaled ltS copies, share rt B-fragments across both
// m's -> 32 MFMA per barrier pair (was 16). Amortizes the fixed per-k0i
// barrier/waitcnt cost F over 2x work: ratio (F+2W)/(2(F+W)). Halves block
// count, rt LDS reads, and lt/rt L2 traffic. Per-m accumulation order is
// unchanged -> absmax bit-identical (0.01367188 canary). LDS 64KB,
// 2 blocks/CU (8 waves).
// ---------------------------------------------------------------------------
__global__ __launch_bounds__(256, 2) void uber_kernel(
        const unsigned short* __restrict__ ltb,
        const unsigned short* __restrict__ rtb,
        const unsigned short* __restrict__ kmb,
        const unsigned short* __restrict__ w1t,
        const float* __restrict__ diag,
        unsigned short* __restrict__ a_all,
        const double* __restrict__ rsq,
        unsigned int* __restrict__ candp,
        float* __restrict__ out) {
    __shared__ __align__(16) unsigned char smem[65536];
    int bx = blockIdx.x;
    int t = threadIdx.x;
    int wave = t >> 6, lane = t & 63;
    int q = lane >> 4, col = lane & 15, kq = q * 8;

    if (bx < 1024) {
        // ================= mpool role (2 m's per block) =================
        int xcd = bx & 7, jj = bx >> 3;     // jj in [0,128)
        int b = xcd * 4 + (jj >> 5);
        int m0 = (jj & 31) * 2;
        unsigned short* ltS0 = (unsigned short*)smem;            // 16384 B, XOR-slot
        unsigned short* ltS1 = (unsigned short*)(smem + 16384);  // 16384 B, XOR-slot
        unsigned short* rtL  = (unsigned short*)(smem + 32768);  // 2 x 16384 B
        int wl = wave & 1, wr = wave >> 1;
        const unsigned short* ltp = ltb + (size_t)b * 65536;
        const unsigned short* rtp = rtb + (size_t)b * 65536;
        const unsigned short* kr0 = kmb + (size_t)m0 * 512;
        const unsigned short* kr1 = kmb + (size_t)(m0 + 1) * 512;
        int srow = t >> 3, cg8 = t & 7, cg = cg8 * 8;
        int gsw = (cg8 ^ (srow & 7)) * 8;
        int wbase = (t & ~63) * 8;

        // prologue: async rt(k0=0) -> buf0; lt/K0/K1 (k0=0) -> regs
        #pragma unroll
        for (int it = 0; it < 4; ++it)
            async16(rtp + (size_t)(it * 32 + srow) * 512 + gsw,
                    rtL + it * 2048 + wbase);
        uint4 pk0 = *(const uint4*)(kr0 + cg);
        uint4 pk1 = *(const uint4*)(kr1 + cg);
        uint4 plt[4];
        #pragma unroll
        for (int it = 0; it < 4; ++it)
            plt[it] = *(const uint4*)(ltp + (size_t)(it * 32 + srow) * 512 + cg);

        float4v acc0[4][4] = {};
        float4v acc1[4][4] = {};
        for (int k0i = 0; k0i < 8; ++k0i) {
            // stage both scaled ltS copies (unpack lt once, scale twice)
            float kf0[8]; unpack8(pk0, kf0);
            float kf1[8]; unpack8(pk1, kf1);
            #pragma unroll
            for (int it = 0; it < 4; ++it) {
                int row = it * 32 + srow;
                float lf[8]; unpack8(plt[it], lf);
                uint4 s0, s1;
                s0.x = pack2_fast(lf[0] * kf0[0], lf[1] * kf0[1]);
                s0.y = pack2_fast(lf[2] * kf0[2], lf[3] * kf0[3]);
                s0.z = pack2_fast(lf[4] * kf0[4], lf[5] * kf0[5]);
                s0.w = pack2_fast(lf[6] * kf0[6], lf[7] * kf0[7]);
                *(uint4*)&ltS0[row * 64 + gsw] = s0;
                s1.x = pack2_fast(lf[0] * kf1[0], lf[1] * kf1[1]);
                s1.y = pack2_fast(lf[2] * kf1[2], lf[3] * kf1[3]);
                s1.z = pack2_fast(lf[4] * kf1[4], lf[5] * kf1[5]);
                s1.w = pack2_fast(lf[6] * kf1[6], lf[7] * kf1[7]);
                *(uint4*)&ltS1[row * 64 + gsw] = s1;
            }
            __syncthreads();   // rt(k0) landed + both ltS staged
            if (k0i < 7) {     // prefetch k0+1: async rt + lt/K regs
                int k0n = (k0i + 1) * 64;
                int bofs = ((k0i + 1) & 1) * 8192;
                #pragma unroll
                for (int it = 0; it < 4; ++it)
                    async16(rtp + (size_t)(it * 32 + srow) * 512 + k0n + gsw,
                            rtL + bofs + it * 2048 + wbase);
                pk0 = *(const uint4*)(kr0 + k0n + cg);
                pk1 = *(const uint4*)(kr1 + k0n + cg);
                #pragma unroll
                for (int it = 0; it < 4; ++it)
                    plt[it] = *(const uint4*)(ltp + (size_t)(it * 32 + srow) * 512 + k0n + cg);
            }
            const unsigned short* rb = rtL + (k0i & 1) * 8192;
            #pragma unroll
            for (int kk = 0; kk < 64; kk += 32) {
                short8 af0[4], af1[4], bfr[4];
                #pragma unroll
                for (int i = 0; i < 4; ++i) {
                    int rowA = wl * 64 + i * 16 + col;
                    int slotA = ((kk >> 3) + q) ^ (rowA & 7);
                    af0[i] = *(const short8*)&ltS0[rowA * 64 + slotA * 8];
                    af1[i] = *(const short8*)&ltS1[rowA * 64 + slotA * 8];
                }
                #pragma unroll
                for (int j = 0; j < 4; ++j) {
                    int row = wr * 64 + j * 16 + col;
                    int slot = ((kk >> 3) + q) ^ (row & 7);
                    bfr[j] = *(const short8*)&rb[row * 64 + slot * 8];
                }
                #pragma unroll
                for (int i = 0; i < 4; ++i)
                    #pragma unroll
                    for (int j = 0; j < 4; ++j) {
                        acc0[i][j] = __builtin_amdgcn_mfma_f32_16x16x32_bf16(af0[i], bfr[j], acc0[i][j], 0, 0, 0);
                        acc1[i][j] = __builtin_amdgcn_mfma_f32_16x16x32_bf16(af1[i], bfr[j], acc1[i][j], 0, 0, 0);
                    }
            }
            __syncthreads();   // before ltS overwrite
        }
        // reductions: mx0/mx1 alias retired ltS0 region (post-loop barrier held)
        float (*mx0)[2] = (float(*)[2])smem;            // 1024 B
        float (*mx1)[2] = (float(*)[2])(smem + 1024);   // 1024 B
        #pragma unroll
        for (int i = 0; i < 4; ++i)
            #pragma unroll
            for (int ii = 0; ii < 4; ++ii) {
                float v0 = fmaxf(fmaxf(acc0[i][0][ii], acc0[i][1][ii]), fmaxf(acc0[i][2][ii], acc0[i][3][ii]));
                float v1 = fmaxf(fmaxf(acc1[i][0][ii], acc1[i][1][ii]), fmaxf(acc1[i][2][ii], acc1[i][3][ii]));
                #pragma unroll
                for (int off = 1; off < 16; off <<= 1) {
                    v0 = fmaxf(v0, __shfl_xor(v0, off, 64));
                    v1 = fmaxf(v1, __shfl_xor(v1, off, 64));
                }
                if (col == 0) {
                    mx0[wl * 64 + i * 16 + q * 4 + ii][wr] = v0;
                    mx1[wl * 64 + i * 16 + q * 4 + ii][wr] = v1;
                }
            }
        __syncthreads();
        if (t < 128) {
            size_t orow = ((size_t)(b * 128 + t)) * 259 + 65;
            out[orow + m0]     = tanhf(fmaxf(mx0[t][0], mx0[t][1]));
            out[orow + m0 + 1] = tanhf(fmaxf(mx1[t][0], mx1[t][1]));
        }

    } else if (bx < 1056) {
        // ================= score role (argmax candidates via MFMA) ===========
        int sb = bx - 1024;                 // [0,32)
        int xcd = sb & 7;
        int b = xcd * 4 + (sb >> 3);
        unsigned short* ltS = (unsigned short*)smem;            // 16384 B
        unsigned short* rtL = (unsigned short*)(smem + 16384);  // 2 x 16384 B
        float* rsqf = (float*)(smem + 49152);                   // 512 B
        unsigned int (*candL)[2] = (unsigned int(*)[2])(smem + 49664); // 1024 B
        int wl = wave & 1, wr = wave >> 1;
        const unsigned short* ltp = ltb + (size_t)b * 65536;
        const unsigned short* rtp = rtb + (size_t)b * 65536;
        int srow = t >> 3, cg8 = t & 7, cg = cg8 * 8;
        int gsw = (cg8 ^ (srow & 7)) * 8;
        int wbase = (t & ~63) * 8;

        #pragma unroll
        for (int it = 0; it < 4; ++it)
            async16(rtp + (size_t)(it * 32 + srow) * 512 + gsw,
                    rtL + it * 2048 + wbase);
        uint4 plt[4];
        #pragma unroll
        for (int it = 0; it < 4; ++it)
            plt[it] = *(const uint4*)(ltp + (size_t)(it * 32 + srow) * 512 + cg);
        if (t < 128) rsqf[t] = (float)rsq[b * 128 + t];

        float4v acc[4][4] = {};
        for (int k0i = 0; k0i < 8; ++k0i) {
            #pragma unroll
            for (int it = 0; it < 4; ++it) {
                int row = it * 32 + srow;
                *(uint4*)&ltS[row * 64 + gsw] = plt[it];   // raw lt (no scale)
            }
            __syncthreads();
            if (k0i < 7) {
                int k0n = (k0i + 1) * 64;
                int bofs = ((k0i + 1) & 1) * 8192;
                #pragma unroll
                for (int it = 0; it < 4; ++it)
                    async16(rtp + (size_t)(it * 32 + srow) * 512 + k0n + gsw,
                            rtL + bofs + it * 2048 + wbase);
                #pragma unroll
                for (int it = 0; it < 4; ++it)
                    plt[it] = *(const uint4*)(ltp + (size_t)(it * 32 + srow) * 512 + k0n + cg);
            }
            const unsigned short* rb = rtL + (k0i & 1) * 8192;
            #pragma unroll
            for (int kk = 0; kk < 64; kk += 32) {
                short8 af[4], bfr[4];
                #pragma unroll
                for (int i = 0; i < 4; ++i) {
                    int rowA = wl * 64 + i * 16 + col;
                    int slotA = ((kk >> 3) + q) ^ (rowA & 7);
                    af[i] = *(const short8*)&ltS[rowA * 64 + slotA * 8];
                }
                #pragma unroll
                for (int j = 0; j < 4; ++j) {
                    int row = wr * 64 + j * 16 + col;
                    int slot = ((kk >> 3) + q) ^ (row & 7);
                    bfr[j] = *(const short8*)&rb[row * 64 + slot * 8];
                }
                #pragma unroll
                for (int i = 0; i < 4; ++i)
                    #pragma unroll
                    for (int j = 0; j < 4; ++j)
                        acc[i][j] = __builtin_amdgcn_mfma_f32_16x16x32_bf16(af[i], bfr[j], acc[i][j], 0, 0, 0);
            }
            __syncthreads();
        }
        // top-2 over this wave's 64 rt-cols per lt-row; 4 cands/row total.
        float rq[4];
        #pragma unroll
        for (int j = 0; j < 4; ++j) rq[j] = rsqf[wr * 64 + j * 16 + col];
        #pragma unroll
        for (int i = 0; i < 4; ++i)
            #pragma unroll
            for (int ii = 0; ii < 4; ++ii) {
                float v1 = -3.0e38f, v2 = -3.0e38f; int i1 = 0, i2 = 1;
                #pragma unroll
                for (int j = 0; j < 4; ++j) {
                    int rc = wr * 64 + j * 16 + col;
                    float s = acc[i][j][ii] * rq[j];
                    if (s > v1) { v2 = v1; i2 = i1; v1 = s; i1 = rc; }
                    else if (s > v2) { v2 = s; i2 = rc; }
                }
                #pragma unroll
                for (int off = 1; off < 16; off <<= 1) {
                    float u1 = __shfl_xor(v1, off, 64); int j1 = __shfl_xor(i1, off, 64);
                    float u2 = __shfl_xor(v2, off, 64); int j2 = __shfl_xor(i2, off, 64);
                    if (u1 > v1) {
                        float ov = v1; int oi = i1;
                        v1 = u1; i1 = j1;
                        if (u2 > ov) { v2 = u2; i2 = j2; } else { v2 = ov; i2 = oi; }
                    } else if (u1 > v2) { v2 = u1; i2 = j1; }
                }
                if (col == 0)
                    candL[wl * 64 + i * 16 + q * 4 + ii][wr] =
                        (unsigned int)i1 | ((unsigned int)i2 << 8);
            }
        __syncthreads();
        if (t < 128)
            candp[b * 128 + t] = candL[t][0] | (candL[t][1] << 16);

    } else {
        // ================= proj role =================
        int R0 = (bx - 1056) * 32;
        unsigned short (*aS)[72] = (unsigned short(*)[72])smem;
        unsigned short (*bS)[72] = (unsigned short(*)[72])(smem + 4608);
        float* diagS = (float*)(smem + 4608 + 18432);
        int wl = wave & 1, wr = wave >> 1;
        if (t < 128) diagS[t] = diag[t];
        const unsigned short* src = (R0 < 4096) ? (ltb + (size_t)R0 * 512) : (rtb + (size_t)(R0 - 4096) * 512);
        float4v acc[4] = {};
        for (int k0 = 0; k0 < 512; k0 += 64) {
            {
                int row = t >> 3, cg = (t & 7) * 8;
                *(uint4*)&aS[row][cg] = *(const uint4*)(src + (size_t)row * 512 + k0 + cg);
            }
            #pragma unroll
            for (int it = 0; it < 4; ++it) {
                int id = it * 256 + t;
                int row = id >> 3, cg = (id & 7) * 8;
                *(uint4*)&bS[row][cg] = *(const uint4*)(w1t + (size_t)row * 512 + k0 + cg);
            }
            __syncthreads();
            #pragma unroll
            for (int kk = 0; kk < 64; kk += 32) {
                short8 af = *(const short8*)&aS[wl * 16 + col][kk + kq];
                #pragma unroll
                for (int j = 0; j < 4; ++j) {
                    short8 bf = *(const short8*)&bS[wr * 64 + j * 16 + col][kk + kq];
                    acc[j] = __builtin_amdgcn_mfma_f32_16x16x32_bf16(af, bf, acc[j], 0, 0, 0);
                }
            }
            __syncthreads();
        }
        bool isLt = (R0 < 4096);
        #pragma unroll
        for (int j = 0; j < 4; ++j)
            #pragma unroll
            for (int ii = 0; ii < 4; ++ii) {
                int rowl = wl * 16 + q * 4 + ii;
                int n = wr * 64 + j * 16 + col;
                float v = tanhf(acc[j][ii]);
                if (isLt) v *= diagS[n];
                a_all[((size_t)(R0 + rowl)) * 128 + n] = f2bf(v);
            }
    }
}

// ---------------------------------------------------------------------------
// K2: tail = attn [0,256) + mpmatch [256,768). R11/R14-verified (3 blocks/CU,
// LDS 53504, f32 attF). Unchanged.
// ---------------------------------------------------------------------------
__global__ __launch_bounds__(512, 6) void tail_kernel(
        const unsigned short* __restrict__ a_all,
        const unsigned short* __restrict__ rtb,
        const unsigned short* __restrict__ rtbT,
        const float* __restrict__ ltf,
        const float* __restrict__ rtf,
        const double* __restrict__ rsq,
        const unsigned short* __restrict__ kb,
        const float* __restrict__ hfw,
        const float* __restrict__ hbw,
        const unsigned int* __restrict__ candp,
        float* __restrict__ out) {
    __shared__ __align__(16) unsigned char smem[53504];
    int bx = blockIdx.x;
    int t = threadIdx.x;
    int wave = t >> 6, lane = t & 63;
    int q = lane >> 4, col = lane & 15, kq = q * 8;

    if (bx < 256) {
        // ================= attn role =================
        int b = bx & 31, lg = bx >> 5;
        int L0 = lg * 16;
        unsigned short (*altS)[136]  = (unsigned short(*)[136])(smem);
        unsigned short (*artS)[136]  = (unsigned short(*)[136])(smem + 4352);
        float (*pmax)[8] = (float(*)[8])(smem + 39168);
        float (*psum)[8] = (float(*)[8])(smem + 39680);
        const unsigned short* kb_att = kb + 2 * 32768;

        if (t < 256) {
            int row = t >> 4, c0 = (t & 15) * 8;
            *(uint4*)&altS[row][c0] = *(const uint4*)(a_all + ((size_t)(b * 128 + L0 + row)) * 128 + c0);
        }
        {
            int row = t >> 2, c0 = (t & 3) * 32;
            const unsigned short* src = a_all + ((size_t)(4096 + b * 128 + row)) * 128 + c0;
            #pragma unroll
            for (int i = 0; i < 4; ++i)
                *(uint4*)&artS[row][c0 + i * 8] = *(const uint4*)(src + i * 8);
        }
        __syncthreads();

        float4v acc = {};
        #pragma unroll
        for (int kk = 0; kk < 128; kk += 32) {
            short8 af = *(const short8*)&altS[col][kk + kq];
            short8 bf = *(const short8*)&artS[wave * 16 + col][kk + kq];
            acc = __builtin_amdgcn_mfma_f32_16x16x32_bf16(af, bf, acc, 0, 0, 0);
        }
        float m4[4], p4[4];
        #pragma unroll
        for (int ii = 0; ii < 4; ++ii) {
            float v = acc[ii];
            #pragma unroll
            for (int off = 1; off < 16; off <<= 1) v = fmaxf(v, __shfl_xor(v, off, 64));
            m4[ii] = v;
        }
        if (col == 0) {
            #pragma unroll
            for (int ii = 0; ii < 4; ++ii) pmax[q * 4 + ii][wave] = m4[ii];
        }
        __syncthreads();
        #pragma unroll
        for (int ii = 0; ii < 4; ++ii) {
            float M = pmax[q * 4 + ii][0];
            #pragma unroll
            for (int w = 1; w < 8; ++w) M = fmaxf(M, pmax[q * 4 + ii][w]);
            p4[ii] = expf(acc[ii] - M);
            float sv = p4[ii];
            #pragma unroll
            for (int off = 1; off < 16; off <<= 1) sv += __shfl_xor(sv, off, 64);
            m4[ii] = sv;
        }
        if (col == 0) {
            #pragma unroll
            for (int ii = 0; ii < 4; ++ii) psum[q * 4 + ii][wave] = m4[ii];
        }
        __syncthreads();
        unsigned short* Pb = (unsigned short*)smem;
        #pragma unroll
        for (int ii = 0; ii < 4; ++ii) {
            float S = psum[q * 4 + ii][0] + psum[q * 4 + ii][1] + psum[q * 4 + ii][2] + psum[q * 4 + ii][3]
                    + psum[q * 4 + ii][4] + psum[q * 4 + ii][5] + psum[q * 4 + ii][6] + psum[q * 4 + ii][7];
            Pb[(q * 4 + ii) * 136 + wave * 16 + col] = f2bf(p4[ii] / S);
        }

        unsigned short* Bc = (unsigned short*)(smem + 4352);
        float* attF = (float*)(smem + 20736);                   // [16][512] f32
        const unsigned short* rtT = rtbT + (size_t)b * 65536;
        for (int cc = 0; cc < 4; ++cc) {
            float4v pacc = {};
            for (int rh = 0; rh < 2; ++rh) {
                #pragma unroll
                for (int k = 0; k < 2; ++k) {
                    int id = (k * 8 + wave) * 64 + lane;        // [0,1024)
                    int row = id >> 3, grp = id & 7;
                    int d   = (row >> 4) * 64 + cc * 16 + (row & 15);
                    int sg  = grp ^ (row & 7);
                    async16(rtT + (size_t)d * 128 + rh * 64 + sg * 8,
                            Bc + (size_t)id * 8);
                }
                __syncthreads();   // chunk landed (first iter: Pb also ready)
                #pragma unroll
                for (int ks = 0; ks < 2; ++ks) {
                    short8 afP = *(const short8*)&Pb[col * 136 + rh * 64 + ks * 32 + kq];
                    int rowB = wave * 16 + col;
                    short8 bfB = *(const short8*)&Bc[rowB * 64 + (((ks * 4 + q) ^ (rowB & 7)) * 8)];
                    pacc = __builtin_amdgcn_mfma_f32_16x16x32_bf16(afP, bfB, pacc, 0, 0, 0);
                }
                __syncthreads();   // guard Bc overwrite
            }
            #pragma unroll
            for (int ii = 0; ii < 4; ++ii)
                attF[(q * 4 + ii) * 512 + wave * 64 + cc * 16 + col] = pacc[ii];
        }
        __syncthreads();           // attF complete

        int l = t >> 5, cd = t & 31;
        float a8[2][8];
        #pragma unroll
        for (int pass = 0; pass < 2; ++pass) {
            *(float4*)&a8[pass][0] = *(const float4*)&attF[l * 512 + pass * 256 + cd * 8];
            *(float4*)&a8[pass][4] = *(const float4*)&attF[l * 512 + pass * 256 + cd * 8 + 4];
        }
        __syncthreads();           // att reads done before region reuse

        unsigned short (*prodsF)[520] = (unsigned short(*)[520])smem;
        unsigned short* Ks = (unsigned short*)(smem + 16640);
        float* red = (float*)(smem + 16640);

        int grow = b * 128 + L0 + l;
        const float* ltrow = ltf + (size_t)grow * 512;
        float csum = 0.f;
        #pragma unroll
        for (int pass = 0; pass < 2; ++pass) {
            int d0 = pass * 256 + cd * 8;
            float lf[8];
            *(float4*)&lf[0] = *(const float4*)(ltrow + d0);
            *(float4*)&lf[4] = *(const float4*)(ltrow + d0 + 4);
            float pf[8];
            #pragma unroll
            for (int k = 0; k < 8; ++k) { pf[k] = lf[k] * a8[pass][k]; csum += pf[k]; }
            uint4 o;
            o.x = pack2(pf[0], pf[1]); o.y = pack2(pf[2], pf[3]);
            o.z = pack2(pf[4], pf[5]); o.w = pack2(pf[6], pf[7]);
            *(uint4*)&prodsF[l][d0] = o;
        }
        #pragma unroll
        for (int off = 1; off < 32; off <<= 1) csum += __shfl_xor(csum, off, 64);
        if (cd == 0) out[(size_t)grow * 259 + 129] = tanhf(csum);

        for (int half = 0; half < 2; ++half) {
            __syncthreads();       // prodsF ready / prior red reads done
            {
                int row = t >> 4, c0 = (t & 15) * 32;
                const unsigned short* src = kb_att + ((size_t)(half * 32 + row)) * 512 + c0;
                #pragma unroll
                for (int i = 0; i < 4; ++i)
                    *(uint4*)&Ks[row * 520 + c0 + i * 8] = *(const uint4*)(src + i * 8);
            }
            __syncthreads();
            float4v pacc[2] = {};
            #pragma unroll
            for (int kk = 0; kk < 64; kk += 32) {
                short8 af = *(const short8*)&prodsF[col][wave * 64 + kk + kq];
                #pragma unroll
                for (int j = 0; j < 2; ++j) {
                    short8 bf = *(const short8*)&Ks[(j * 16 + col) * 520 + wave * 64 + kk + kq];
                    pacc[j] = __builtin_amdgcn_mfma_f32_16x16x32_bf16(af, bf, pacc[j], 0, 0, 0);
                }
            }
            __syncthreads();       // all Ks reads done before red overwrites
            #pragma unroll
            for (int j = 0; j < 2; ++j)
                #pragma unroll
                for (int ii = 0; ii < 4; ++ii)
                    red[((wave * 2 + j) * 16 + q * 4 + ii) * 16 + col] = pacc[j][ii];
            __syncthreads();
            {
                int ll = t >> 5, jm = t & 31;
                int j = jm >> 4, mc = jm & 15;
                float sv = 0.f;
                #pragma unroll
                for (int w = 0; w < 8; ++w) sv += red[((w * 2 + j) * 16 + ll) * 16 + mc];
                out[((size_t)(b * 128 + L0 + ll)) * 259 + 130 + half * 32 + jm] = tanhf(sv);
            }
        }

    } else {
        // ================= mpmatch role (sequential 32-m halves) =============
        int idB = bx - 256;
        int lg = idB & 7, b = (idB >> 3) & 31;
        int mode = (idB >> 8) ? 2 : 0;
        int L0 = lg * 16;
        unsigned short (*prods)[520] = (unsigned short(*)[520])smem;   // [0,16640)
        unsigned short* Ks = (unsigned short*)(smem + 16640);          // [16640,49920)
        float* red = (float*)(smem + 16640);                           // aliases Ks
        double* dvs2 = (double*)(smem + 49920);                        // 512
        int* idxl = (int*)(smem + 50432);                              // 64
        const unsigned short* Kp = kb + (size_t)((mode == 0) ? 0 : 3 * 32768);
        int obase = (mode == 0) ? 0 : 194;

        if (mode == 2) {
            int dotid = t >> 3, sub = t & 7;     // 64 dots x 8 threads
            int l = dotid >> 2, c = dotid & 3;
            unsigned int cpl = candp[b * 128 + L0 + l];
            int rr0 = (cpl >> (c * 8)) & 0xff;
            const float* lrow = ltf + ((size_t)(b * 128 + L0 + l)) * 512;
            const float* rrow = rtf + ((size_t)(b * 128 + rr0)) * 512;
            double sv = 0.0;
            #pragma unroll 8
            for (int k = 0; k < 64; ++k) {
                int d = sub * 64 + k;
                sv = fma((double)lrow[d], (double)rrow[d], sv);
            }
            #pragma unroll
            for (int off = 1; off < 8; off <<= 1) sv += __shfl_xor(sv, off, 64);
            if (sub == 0) dvs2[dotid] = sv * rsq[b * 128 + rr0];
            __syncthreads();
            if (t < 16) {
                unsigned int cl = candp[b * 128 + L0 + t];
                int bi = 256; double bv = -1.0e300;
                #pragma unroll
                for (int cc = 0; cc < 4; ++cc) {
                    int rr = (cl >> (cc * 8)) & 0xff;
                    double v = dvs2[t * 4 + cc];
                    if (v > bv || (v == bv && rr < bi)) { bv = v; bi = rr; }
                }
                idxl[t] = bi;
            }
            __syncthreads();
        }

        if (t < 256) {
            int l = t >> 4, c = t & 15;
            int grow = b * 128 + L0 + l;
            const float* ltrow = ltf + (size_t)grow * 512;
            const unsigned short* avrow = 0;
            if (mode == 2) avrow = rtb + ((size_t)(b * 128 + idxl[l])) * 512;
            float csum = 0.f;
            #pragma unroll
            for (int pass = 0; pass < 4; ++pass) {
                int d0 = pass * 128 + c * 8;
                float lf[8], af[8], pf[8];
                *(float4*)&lf[0] = *(const float4*)(ltrow + d0);
                *(float4*)&lf[4] = *(const float4*)(ltrow + d0 + 4);
                if (mode == 0) {
                    const float* h = (d0 < 256) ? (hfw + b * 256 + d0) : (hbw + b * 256 + d0 - 256);
                    *(float4*)&af[0] = *(const float4*)h;
                    *(float4*)&af[4] = *(const float4*)(h + 4);
                } else {
                    uint4 av = *(const uint4*)(avrow + d0);
                    unpack8(av, af);
                }
                #pragma unroll
                for (int k = 0; k < 8; ++k) { pf[k] = lf[k] * af[k]; csum += pf[k]; }
                uint4 o;
                o.x = pack2(pf[0], pf[1]); o.y = pack2(pf[2], pf[3]);
                o.z = pack2(pf[4], pf[5]); o.w = pack2(pf[6], pf[7]);
                *(uint4*)&prods[l][d0] = o;
            }
            #pragma unroll
            for (int off = 1; off < 16; off <<= 1) csum += __shfl_xor(csum, off, 64);
            if (c == 0) out[(size_t)grow * 259 + obase] = tanhf(csum);
        }
        for (int half = 0; half < 2; ++half) {
            if (half == 1) __syncthreads();    // prior red reads done before restage
            {   // stage 32 K rows (512 threads, 32B each)
                int row = t >> 4, c0 = (t & 15) * 32;
                const unsigned short* src = Kp + ((size_t)(half * 32 + row)) * 512 + c0;
                #pragma unroll
                for (int i = 0; i < 4; ++i)
                    *(uint4*)&Ks[row * 520 + c0 + i * 8] = *(const uint4*)(src + i * 8);
            }
            __syncthreads();   // prods + Ks ready
            float4v acc2[2] = {};
            #pragma unroll
            for (int kk = 0; kk < 64; kk += 32) {
                short8 af = *(const short8*)&prods[col][wave * 64 + kk + kq];
                #pragma unroll
                for (int j = 0; j < 2; ++j) {
                    short8 bf = *(const short8*)&Ks[(j * 16 + col) * 520 + wave * 64 + kk + kq];
                    acc2[j] = __builtin_amdgcn_mfma_f32_16x16x32_bf16(af, bf, acc2[j], 0, 0, 0);
                }
            }
            __syncthreads();   // all Ks reads done before red overwrites
            #pragma unroll
            for (int j = 0; j < 2; ++j)
                #pragma unroll
                for (int ii = 0; ii < 4; ++ii)
                    red[((wave * 2 + j) * 16 + q * 4 + ii) * 16 + col] = acc2[j][ii];
            __syncthreads();   // red ready
            {
                int ll = t >> 5, jm = t & 31;
                int j = jm >> 4, mc = jm & 15;
                float sv = 0.f;
                #pragma unroll
                for (int w = 0; w < 8; ++w) sv += red[((w * 2 + j) * 16 + ll) * 16 + mc];
                out[((size_t)(b * 128 + L0 + ll)) * 259 + obase + 1 + half * 32 + jm] = tanhf(sv);
            }
        }
    }
}

// ---------------------------------------------------------------------------
extern "C" void kernel_launch(void* const* d_in, const int* in_sizes, int n_in,
                              void* d_out, int out_size, void* d_ws, size_t ws_size,
                              hipStream_t stream) {
    const float* lt  = (const float*)d_in[0];
    const float* rt  = (const float*)d_in[3];
    const float* hfw = (const float*)d_in[4];
    const float* hbw = (const float*)d_in[5];
    const float* kf  = (const float*)d_in[6];
    const float* kmp = (const float*)d_in[7];
    const float* w1  = (const float*)d_in[8];
    const float* dia = (const float*)d_in[9];
    const float* ka  = (const float*)d_in[10];
    const float* km  = (const float*)d_in[11];
    float* out = (float*)d_out;

    char* wsb = (char*)d_ws;
    unsigned short* ltb16 = (unsigned short*)(wsb);                        // 4 MB
    unsigned short* rtb16 = (unsigned short*)(wsb + 4194304);              // 4 MB
    unsigned short* kb16  = (unsigned short*)(wsb + 8388608);              // 256 KB
    unsigned short* w1t   = (unsigned short*)(wsb + 8650752);              // 128 KB
    unsigned short* a_all = (unsigned short*)(wsb + 8781824);              // 2 MB
    unsigned short* rtbT  = (unsigned short*)(wsb + 10878976);             // 4 MB
    double*         rsq   = (double*)(wsb + 15073280);                     // 32 KB
    unsigned int*   candp = (unsigned int*)(wsb + 15106048);               // 16 KB

    prep_kernel<<<3264, 256, 0, stream>>>(lt, rt, kf, kmp, ka, km, w1, ltb16, rtb16, kb16, w1t, rtbT, rsq);
    uber_kernel<<<1312, 256, 0, stream>>>(ltb16, rtb16, kb16 + 32768, w1t, dia, a_all,
                                          rsq, candp, out);
    tail_kernel<<<768, 512, 0, stream>>>(a_all, rtb16, rtbT, lt, rt, rsq, kb16, hfw, hbw, candp, out);
}